// Round 13
// baseline (319.043 us; speedup 1.0000x reference)
//
#include <hip/hip_runtime.h>
#include <hip/hip_bf16.h>
#include <cstdint>
#include <cstddef>

typedef _Float16 h2 __attribute__((ext_vector_type(2)));
typedef _Float16 h4 __attribute__((ext_vector_type(4)));
typedef _Float16 h8 __attribute__((ext_vector_type(8)));
typedef float    f4 __attribute__((ext_vector_type(4)));

#define SEQ 4096
#define EMB 1280
#define NH 16
#define HD 80
#define QKV_LD 3840

// ---------------- fp32 -> f16 convert ----------------
__global__ __launch_bounds__(256) void k_convert(const float* __restrict__ in,
                                                 _Float16* __restrict__ out, int n4) {
  int i = blockIdx.x * 256 + threadIdx.x;
  if (i < n4) {
    f4 v = ((const f4*)in)[i];
    h4 o; o[0] = (_Float16)v[0]; o[1] = (_Float16)v[1];
    o[2] = (_Float16)v[2]; o[3] = (_Float16)v[3];
    ((h4*)out)[i] = o;
  }
}

// ---------------- transpose + convert: in (R,C) fp32 -> out (C,R) f16 ----------------
__global__ __launch_bounds__(256) void k_transpose(const float* __restrict__ in,
                                                   _Float16* __restrict__ out, int R, int C) {
  __shared__ _Float16 tile[64][68];
  int ct = C >> 6;
  int rB = (blockIdx.x / ct) << 6;
  int cB = (blockIdx.x % ct) << 6;
#pragma unroll 4
  for (int i = 0; i < 16; i++) {
    int idx = i * 256 + threadIdx.x;
    int r = idx >> 6, c = idx & 63;
    tile[r][c] = (_Float16)in[(size_t)(rB + r) * C + cB + c];
  }
  __syncthreads();
#pragma unroll 4
  for (int i = 0; i < 16; i++) {
    int idx = i * 256 + threadIdx.x;
    int c = idx >> 6, r = idx & 63;
    out[(size_t)(cB + c) * R + rB + r] = tile[r][c];
  }
}

// ---------------- GEMM (round-1 VERIFIED): C(M,N) = A(M,K) * B(N,K)^T + bias ----------------
template <bool OUT_F32>
__global__ __launch_bounds__(256) void k_gemm(const _Float16* __restrict__ A,
                                              const _Float16* __restrict__ B,
                                              const float* __restrict__ bias,
                                              void* __restrict__ Cout,
                                              int M, int N, int K) {
  __shared__ _Float16 As[128][40];
  __shared__ _Float16 Bs[128][40];
  int tid = threadIdx.x;
  int lane = tid & 63, wave = tid >> 6;
  int wr = wave >> 1, wc = wave & 1;
  int l15 = lane & 15, g = lane >> 4;
  int nt = N >> 7;
  int mBase = (blockIdx.x / nt) << 7;
  int nBase = (blockIdx.x % nt) << 7;

  f4 acc[4][4];
#pragma unroll
  for (int i = 0; i < 4; i++)
#pragma unroll
    for (int j = 0; j < 4; j++) acc[i][j] = (f4)0.f;

  for (int kt = 0; kt < K; kt += 32) {
    __syncthreads();
#pragma unroll
    for (int i = 0; i < 2; i++) {
      int p = i * 256 + tid;   // 0..511
      int r = p >> 2, c = p & 3;
      *(h8*)&As[r][c * 8] = *(const h8*)(A + (size_t)(mBase + r) * K + kt + c * 8);
      *(h8*)&Bs[r][c * 8] = *(const h8*)(B + (size_t)(nBase + r) * K + kt + c * 8);
    }
    __syncthreads();
    h8 af[4], bf[4];
#pragma unroll
    for (int i = 0; i < 4; i++) af[i] = *(const h8*)&As[wr * 64 + i * 16 + l15][g * 8];
#pragma unroll
    for (int j = 0; j < 4; j++) bf[j] = *(const h8*)&Bs[wc * 64 + j * 16 + l15][g * 8];
#pragma unroll
    for (int i = 0; i < 4; i++)
#pragma unroll
      for (int j = 0; j < 4; j++)
        acc[i][j] = __builtin_amdgcn_mfma_f32_16x16x32_f16(bf[j], af[i], acc[i][j], 0, 0, 0);
  }

#pragma unroll
  for (int i = 0; i < 4; i++)
#pragma unroll
    for (int j = 0; j < 4; j++) {
      int row  = mBase + wr * 64 + i * 16 + l15;
      int colb = nBase + wc * 64 + j * 16 + g * 4;
      f4 bv = *(const f4*)(bias + colb);
      f4 v  = acc[i][j] + bv;
      if (OUT_F32) {
        *(f4*)&((float*)Cout)[(size_t)row * N + colb] = v;
      } else {
        h4 o; o[0] = (_Float16)v[0]; o[1] = (_Float16)v[1];
        o[2] = (_Float16)v[2]; o[3] = (_Float16)v[3];
        *(h4*)&((_Float16*)Cout)[(size_t)row * N + colb] = o;
      }
    }
}

// ---------------- RoPE: in-place f16. Q gets 80^-0.5 * log2(e) folded in ----------------
// COUPLED with k_attn's exp2-domain softmax. (Verified R11/R12.)
__global__ __launch_bounds__(256) void k_rope(_Float16* __restrict__ qkv,
                                              const float* __restrict__ cosb,
                                              const float* __restrict__ sinb) {
  int idx = blockIdx.x * 256 + threadIdx.x;  // 4096*16*10
  int s = idx / 160;
  int rem = idx % 160;
  int h = rem / 10;
  int d4 = (rem % 10) * 4;
  const float qscale = 0.16129821086f;  // 80^-0.5 * log2(e)
  f4 c1 = *(const f4*)(cosb + s * 80 + d4);
  f4 s1 = *(const f4*)(sinb + s * 80 + d4);
  f4 c2 = *(const f4*)(cosb + s * 80 + d4 + 40);
  f4 s2 = *(const f4*)(sinb + s * 80 + d4 + 40);
  {
    _Float16* p = qkv + (size_t)s * QKV_LD + h * HD + d4;
    h4 x1 = *(h4*)p, x2 = *(h4*)(p + 40);
    h4 o1, o2;
#pragma unroll
    for (int j = 0; j < 4; j++) {
      float a = (float)x1[j], b = (float)x2[j];
      o1[j] = (_Float16)((a * c1[j] - b * s1[j]) * qscale);
      o2[j] = (_Float16)((b * c2[j] + a * s2[j]) * qscale);
    }
    *(h4*)p = o1; *(h4*)(p + 40) = o2;
  }
  {
    _Float16* p = qkv + (size_t)s * QKV_LD + EMB + h * HD + d4;
    h4 x1 = *(h4*)p, x2 = *(h4*)(p + 40);
    h4 o1, o2;
#pragma unroll
    for (int j = 0; j < 4; j++) {
      float a = (float)x1[j], b = (float)x2[j];
      o1[j] = (_Float16)(a * c1[j] - b * s1[j]);
      o2[j] = (_Float16)(b * c2[j] + a * s2[j]);
    }
    *(h4*)p = o1; *(h4*)(p + 40) = o2;
  }
}

// ---------------- V global transpose: VT[(h*80+d)*SEQ + s] = V[s][h*80+d] ----------------
__global__ __launch_bounds__(256) void k_vt(const _Float16* __restrict__ qkv,
                                            _Float16* __restrict__ vt) {
  __shared__ __align__(16) _Float16 T[64][88];  // 176B rows: h8 writes 16B-aligned
  int tid = threadIdx.x;
  int h = blockIdx.x & 15;
  int sb = (blockIdx.x >> 4) << 6;
  const _Float16* src = qkv + 2 * EMB + h * HD;
#pragma unroll
  for (int i = 0; i < 3; ++i) {
    int u = i * 256 + tid;  // 640 h8 units: row=u/10, c8=u%10
    if (u < 640) {
      int row = u / 10, c8 = u % 10;
      *(h8*)&T[row][c8 * 8] = *(const h8*)(src + (size_t)(sb + row) * QKV_LD + c8 * 8);
    }
  }
  __syncthreads();
#pragma unroll
  for (int i = 0; i < 5; ++i) {
    int u = i * 256 + tid;  // 1280 h4 units: d=u>>4, s4=u&15
    int d = u >> 4, s4 = u & 15;
    h4 o;
#pragma unroll
    for (int j = 0; j < 4; ++j) o[j] = T[s4 * 4 + j][d];
    *(h4*)(vt + (size_t)(h * HD + d) * SEQ + sb + s4 * 4) = o;
  }
}

// ---------------- Flash attention v13: R12 structure (KVBLK=128, 8 waves, XCD map,
// exp2 softmax) with V LDS reverted to the R11-PROVEN low-conflict geometry:
// two [80][68] halves (stride 34 dw == 2 mod 32), h4-pair writes, R7-exact reads.
__global__ __launch_bounds__(512) void k_attn(const _Float16* __restrict__ qkv,
                                              const _Float16* __restrict__ vt,
                                              _Float16* __restrict__ out) {
  __shared__ _Float16 Kl[128][84];   // 168B rows (R7/R12-verified conflict-free)
  __shared__ _Float16 VtA[80][68];   // kv 0..63   (R11-verified geometry)
  __shared__ _Float16 VtB[80][68];   // kv 64..127
  int tid = threadIdx.x;
  int lane = tid & 63, wave = tid >> 6;   // wave 0..7
  int l15 = lane & 15, g = lane >> 4;
  int bid = blockIdx.x;
  // XCD-aware bijective remap (512 blocks): xcd = bid&7 gets heads {2*xcd, 2*xcd+1}
  int xcd = bid & 7, rest = bid >> 3;
  int h = (xcd << 1) | (rest & 1);
  int qb = rest >> 1;                     // 0..31

  // Q fragments (B-operand layout): Q[q=l15][d = ks*16 + g*4 + j]
  int qrow = qb * 128 + wave * 16 + l15;
  const _Float16* qp = qkv + (size_t)qrow * QKV_LD + h * HD;
  h4 qf[5];
#pragma unroll
  for (int ks = 0; ks < 5; ks++) qf[ks] = *(const h4*)(qp + ks * 16 + g * 4);

  // K staging: 2560 h4-units (128 rows x 20): u = i*512 + tid, row=u/20, q4=u%20
  const _Float16* gk[5];
  _Float16* lk[5];
#pragma unroll
  for (int i = 0; i < 5; i++) {
    int u = i * 512 + tid;
    gk[i] = qkv + EMB + h * HD + (size_t)(u / 20) * QKV_LD + (u % 20) * 4;
    lk[i] = &Kl[u / 20][(u % 20) * 4];
  }
  // V staging: 1280 h8-units over two halves; unit u: hh=u/640, v=u%640, d=v>>3, c=v&7
  //   u0 = tid (hh=0); u1 = 512+tid (hh=0 rows 64-79 for tid<128, else hh=1 rows 0-47);
  //   u2 = 1024+tid, tid<256 (hh=1 rows 48-79). Covers all units exactly once.
  int d0 = tid >> 3, c0 = tid & 7;
  int hh1 = (tid >= 128) ? 1 : 0;
  int v1 = hh1 ? (tid - 128) : (512 + tid);
  int d1 = v1 >> 3, c1 = v1 & 7;
  int d2 = 48 + (tid >> 3), c2 = tid & 7;   // guarded tid<256
  const _Float16* gv0 = vt + (size_t)(h * HD + d0) * SEQ + c0 * 8;
  const _Float16* gv1 = vt + (size_t)(h * HD + d1) * SEQ + hh1 * 64 + c1 * 8;
  const _Float16* gv2 = vt + (size_t)(h * HD + d2) * SEQ + 64 + c2 * 8;
  _Float16* lv0 = &VtA[d0][c0 * 8];
  _Float16* lv1 = hh1 ? &VtB[d1][c1 * 8] : &VtA[d1][c1 * 8];
  _Float16* lv2 = &VtB[d2][c2 * 8];

  float m = -1e30f, lsum = 0.f;
  f4 O[5];
#pragma unroll
  for (int d = 0; d < 5; d++) O[d] = (f4)0.f;

  for (int t = 0; t < 32; t++) {
    __syncthreads();
    // stage K tile [128][80] (linear, conflict-free 168B rows)
    size_t ka = (size_t)t * (size_t)(128 * QKV_LD);
    int va = t * 128;
    *(h4*)lk[0] = *(const h4*)(gk[0] + ka);
    *(h4*)lk[1] = *(const h4*)(gk[1] + ka);
    *(h4*)lk[2] = *(const h4*)(gk[2] + ka);
    *(h4*)lk[3] = *(const h4*)(gk[3] + ka);
    *(h4*)lk[4] = *(const h4*)(gk[4] + ka);
    // stage V^T tile as two [80][64] halves (h4-pair writes, R11 pattern)
    {
      h8 v0 = *(const h8*)(gv0 + va);
      h8 v1 = *(const h8*)(gv1 + va);
      h4 a, b;
      a[0] = v0[0]; a[1] = v0[1]; a[2] = v0[2]; a[3] = v0[3];
      b[0] = v0[4]; b[1] = v0[5]; b[2] = v0[6]; b[3] = v0[7];
      *(h4*)lv0 = a; *(h4*)(lv0 + 4) = b;
      a[0] = v1[0]; a[1] = v1[1]; a[2] = v1[2]; a[3] = v1[3];
      b[0] = v1[4]; b[1] = v1[5]; b[2] = v1[6]; b[3] = v1[7];
      *(h4*)lv1 = a; *(h4*)(lv1 + 4) = b;
      if (tid < 256) {
        h8 v2 = *(const h8*)(gv2 + va);
        a[0] = v2[0]; a[1] = v2[1]; a[2] = v2[2]; a[3] = v2[3];
        b[0] = v2[4]; b[1] = v2[5]; b[2] = v2[6]; b[3] = v2[7];
        *(h4*)lv2 = a; *(h4*)(lv2 + 4) = b;
      }
    }
    __syncthreads();

    // QK^T -> S^T tile (128 kv x 16 q), fp32 (R7-exact fragment maps, kvs 0..7)
    f4 st[8];
#pragma unroll
    for (int kvs = 0; kvs < 8; kvs++) st[kvs] = (f4)0.f;
#pragma unroll
    for (int kvs = 0; kvs < 8; kvs++)
#pragma unroll
      for (int ks = 0; ks < 5; ks++) {
        h4 a = *(const h4*)&Kl[kvs * 16 + l15][ks * 16 + g * 4];
        st[kvs] = __builtin_amdgcn_mfma_f32_16x16x16f16(a, qf[ks], st[kvs], 0, 0, 0);
      }

    // online softmax — exp2 domain (log2e folded into Q), full rescale per tile
    float pm = -1e30f;
#pragma unroll
    for (int kvs = 0; kvs < 8; kvs++)
#pragma unroll
      for (int r = 0; r < 4; r++) pm = fmaxf(pm, st[kvs][r]);
    pm = fmaxf(pm, __shfl_xor(pm, 16));
    pm = fmaxf(pm, __shfl_xor(pm, 32));
    float mn = fmaxf(m, pm);
    float fac = __builtin_amdgcn_exp2f(m - mn);
    float rs = 0.f;
    h4 pb[8];
#pragma unroll
    for (int kvs = 0; kvs < 8; kvs++)
#pragma unroll
      for (int r = 0; r < 4; r++) {
        float p = __builtin_amdgcn_exp2f(st[kvs][r] - mn);
        rs += p;
        pb[kvs][r] = (_Float16)p;
      }
    rs += __shfl_xor(rs, 16);
    rs += __shfl_xor(rs, 32);
    lsum = lsum * fac + rs;
    m = mn;
#pragma unroll
    for (int d = 0; d < 5; d++) O[d] *= fac;

    // PV (R7-exact maps): O^T[d][q] += V^T[d][kv] * P^T[kv][q]; A/B half by kvs
#pragma unroll
    for (int d5 = 0; d5 < 5; d5++)
#pragma unroll
      for (int kvs = 0; kvs < 8; kvs++) {
        const _Float16* vr = (kvs < 4)
            ? &VtA[d5 * 16 + l15][(kvs & 3) * 16 + g * 4]
            : &VtB[d5 * 16 + l15][(kvs & 3) * 16 + g * 4];
        h4 a = *(const h4*)vr;
        O[d5] = __builtin_amdgcn_mfma_f32_16x16x16f16(a, pb[kvs], O[d5], 0, 0, 0);
      }
  }

  float inv = 1.0f / lsum;
  _Float16* op = out + (size_t)qrow * EMB + h * HD;
#pragma unroll
  for (int d5 = 0; d5 < 5; d5++) {
    h4 o;
#pragma unroll
    for (int r = 0; r < 4; r++) o[r] = (_Float16)(O[d5][r] * inv);
    *(h4*)(op + d5 * 16 + g * 4) = o;
  }
}

extern "C" void kernel_launch(void* const* d_in, const int* in_sizes, int n_in,
                              void* d_out, int out_size, void* d_ws, size_t ws_size,
                              hipStream_t stream) {
  const float* hidden = (const float*)d_in[0];
  const float* cosb   = (const float*)d_in[1];
  const float* sinb   = (const float*)d_in[2];
  const float* Wqkv   = (const float*)d_in[3];
  const float* bqkv   = (const float*)d_in[4];
  const float* Wproj  = (const float*)d_in[5];
  const float* bproj  = (const float*)d_in[6];

  // ws layout — max footprint 55,050,240 B (round-1/7 PROVEN bound):
  //   Ah   @ 0        : 10485760  hidden f16, later attention output
  //   WqT  @ 10485760 :  9830400  dead after QKV GEMM
  //   VT   @ 10485760 : 10485760  written by k_vt AFTER the GEMM (over WqT)
  //   WpT  @ 20316160 :  3276800  written AFTER attention (over VT tail; VT dead)
  //   qkvb @ 23592960 : 31457280
  char* ws = (char*)d_ws;
  _Float16* Ah   = (_Float16*)(ws);
  _Float16* WqT  = (_Float16*)(ws + 10485760);
  _Float16* VT   = (_Float16*)(ws + 10485760);
  _Float16* WpT  = (_Float16*)(ws + 20316160);
  _Float16* qkvb = (_Float16*)(ws + 23592960);

  k_convert<<<SEQ * EMB / 4 / 256, 256, 0, stream>>>(hidden, Ah, SEQ * EMB / 4);
  k_transpose<<<(EMB / 64) * (3 * EMB / 64), 256, 0, stream>>>(Wqkv, WqT, EMB, 3 * EMB);
  k_gemm<false><<<(SEQ / 128) * (3 * EMB / 128), 256, 0, stream>>>(
      Ah, WqT, bqkv, (void*)qkvb, SEQ, 3 * EMB, EMB);
  k_rope<<<(SEQ * NH * 10) / 256, 256, 0, stream>>>(qkvb, cosb, sinb);
  k_vt<<<NH * (SEQ / 64), 256, 0, stream>>>(qkvb, VT);            // VT over dead WqT
  k_attn<<<NH * (SEQ / 128), 512, 0, stream>>>(qkvb, VT, Ah);     // Ah's hidden is dead
  k_transpose<<<(EMB / 64) * (EMB / 64), 256, 0, stream>>>(Wproj, WpT, EMB, EMB);
  k_gemm<true><<<(SEQ / 128) * (EMB / 128), 256, 0, stream>>>(
      Ah, WpT, bproj, d_out, SEQ, EMB, EMB);
}

// Round 15
// 283.871 us; speedup vs baseline: 1.1239x; 1.1239x over previous
//
#include <hip/hip_runtime.h>
#include <hip/hip_bf16.h>
#include <cstdint>
#include <cstddef>

typedef _Float16 h2 __attribute__((ext_vector_type(2)));
typedef _Float16 h4 __attribute__((ext_vector_type(4)));
typedef _Float16 h8 __attribute__((ext_vector_type(8)));
typedef float    f4 __attribute__((ext_vector_type(4)));

#define SEQ 4096
#define EMB 1280
#define NH 16
#define HD 80
#define QKV_LD 3840

// ---------------- fp32 -> f16 convert ----------------
__global__ __launch_bounds__(256) void k_convert(const float* __restrict__ in,
                                                 _Float16* __restrict__ out, int n4) {
  int i = blockIdx.x * 256 + threadIdx.x;
  if (i < n4) {
    f4 v = ((const f4*)in)[i];
    h4 o; o[0] = (_Float16)v[0]; o[1] = (_Float16)v[1];
    o[2] = (_Float16)v[2]; o[3] = (_Float16)v[3];
    ((h4*)out)[i] = o;
  }
}

// ---------------- transpose + convert: in (R,C) fp32 -> out (C,R) f16 ----------------
__global__ __launch_bounds__(256) void k_transpose(const float* __restrict__ in,
                                                   _Float16* __restrict__ out, int R, int C) {
  __shared__ _Float16 tile[64][68];
  int ct = C >> 6;
  int rB = (blockIdx.x / ct) << 6;
  int cB = (blockIdx.x % ct) << 6;
#pragma unroll 4
  for (int i = 0; i < 16; i++) {
    int idx = i * 256 + threadIdx.x;
    int r = idx >> 6, c = idx & 63;
    tile[r][c] = (_Float16)in[(size_t)(rB + r) * C + cB + c];
  }
  __syncthreads();
#pragma unroll 4
  for (int i = 0; i < 16; i++) {
    int idx = i * 256 + threadIdx.x;
    int c = idx >> 6, r = idx & 63;
    out[(size_t)(cB + c) * R + rB + r] = tile[r][c];
  }
}

// ---------------- GEMM v15: verified stage->BAR->compute->BAR skeleton, BK 32->64.
// Per K-step: stage 128x64 A + B (4 h8/thread/matrix), one barrier pair, two K=32
// MFMA sub-steps. Barrier pairs 40 -> 20 for K=1280. Row stride 72 halves ->
// 2-way banks (free); all 16B accesses aligned (144B rows).
template <bool OUT_F32>
__global__ __launch_bounds__(256) void k_gemm(const _Float16* __restrict__ A,
                                              const _Float16* __restrict__ B,
                                              const float* __restrict__ bias,
                                              void* __restrict__ Cout,
                                              int M, int N, int K) {
  __shared__ _Float16 As[128][72];
  __shared__ _Float16 Bs[128][72];
  int tid = threadIdx.x;
  int lane = tid & 63, wave = tid >> 6;
  int wr = wave >> 1, wc = wave & 1;
  int l15 = lane & 15, g = lane >> 4;
  int nt = N >> 7;
  int mBase = (blockIdx.x / nt) << 7;
  int nBase = (blockIdx.x % nt) << 7;

  f4 acc[4][4];
#pragma unroll
  for (int i = 0; i < 4; i++)
#pragma unroll
    for (int j = 0; j < 4; j++) acc[i][j] = (f4)0.f;

  for (int kt = 0; kt < K; kt += 64) {
    __syncthreads();
#pragma unroll
    for (int i = 0; i < 4; i++) {
      int p = i * 256 + tid;   // 0..1023: r = p>>3, c = p&7
      int r = p >> 3, c = p & 7;
      *(h8*)&As[r][c * 8] = *(const h8*)(A + (size_t)(mBase + r) * K + kt + c * 8);
      *(h8*)&Bs[r][c * 8] = *(const h8*)(B + (size_t)(nBase + r) * K + kt + c * 8);
    }
    __syncthreads();
#pragma unroll
    for (int kk = 0; kk < 2; kk++) {
      h8 af[4], bf[4];
#pragma unroll
      for (int i = 0; i < 4; i++)
        af[i] = *(const h8*)&As[wr * 64 + i * 16 + l15][kk * 32 + g * 8];
#pragma unroll
      for (int j = 0; j < 4; j++)
        bf[j] = *(const h8*)&Bs[wc * 64 + j * 16 + l15][kk * 32 + g * 8];
#pragma unroll
      for (int i = 0; i < 4; i++)
#pragma unroll
        for (int j = 0; j < 4; j++)
          acc[i][j] = __builtin_amdgcn_mfma_f32_16x16x32_f16(bf[j], af[i], acc[i][j], 0, 0, 0);
    }
  }

#pragma unroll
  for (int i = 0; i < 4; i++)
#pragma unroll
    for (int j = 0; j < 4; j++) {
      int row  = mBase + wr * 64 + i * 16 + l15;
      int colb = nBase + wc * 64 + j * 16 + g * 4;
      f4 bv = *(const f4*)(bias + colb);
      f4 v  = acc[i][j] + bv;
      if (OUT_F32) {
        *(f4*)&((float*)Cout)[(size_t)row * N + colb] = v;
      } else {
        h4 o; o[0] = (_Float16)v[0]; o[1] = (_Float16)v[1];
        o[2] = (_Float16)v[2]; o[3] = (_Float16)v[3];
        *(h4*)&((_Float16*)Cout)[(size_t)row * N + colb] = o;
      }
    }
}

// ---------------- RoPE: in-place f16. Q gets 80^-0.5 * log2(e) folded in ----------------
// COUPLED with k_attn's exp2-domain softmax. (Verified R11/R12.)
__global__ __launch_bounds__(256) void k_rope(_Float16* __restrict__ qkv,
                                              const float* __restrict__ cosb,
                                              const float* __restrict__ sinb) {
  int idx = blockIdx.x * 256 + threadIdx.x;  // 4096*16*10
  int s = idx / 160;
  int rem = idx % 160;
  int h = rem / 10;
  int d4 = (rem % 10) * 4;
  const float qscale = 0.16129821086f;  // 80^-0.5 * log2(e)
  f4 c1 = *(const f4*)(cosb + s * 80 + d4);
  f4 s1 = *(const f4*)(sinb + s * 80 + d4);
  f4 c2 = *(const f4*)(cosb + s * 80 + d4 + 40);
  f4 s2 = *(const f4*)(sinb + s * 80 + d4 + 40);
  {
    _Float16* p = qkv + (size_t)s * QKV_LD + h * HD + d4;
    h4 x1 = *(h4*)p, x2 = *(h4*)(p + 40);
    h4 o1, o2;
#pragma unroll
    for (int j = 0; j < 4; j++) {
      float a = (float)x1[j], b = (float)x2[j];
      o1[j] = (_Float16)((a * c1[j] - b * s1[j]) * qscale);
      o2[j] = (_Float16)((b * c2[j] + a * s2[j]) * qscale);
    }
    *(h4*)p = o1; *(h4*)(p + 40) = o2;
  }
  {
    _Float16* p = qkv + (size_t)s * QKV_LD + EMB + h * HD + d4;
    h4 x1 = *(h4*)p, x2 = *(h4*)(p + 40);
    h4 o1, o2;
#pragma unroll
    for (int j = 0; j < 4; j++) {
      float a = (float)x1[j], b = (float)x2[j];
      o1[j] = (_Float16)(a * c1[j] - b * s1[j]);
      o2[j] = (_Float16)(b * c2[j] + a * s2[j]);
    }
    *(h4*)p = o1; *(h4*)(p + 40) = o2;
  }
}

// ---------------- V global transpose: VT[(h*80+d)*SEQ + s] = V[s][h*80+d] ----------------
__global__ __launch_bounds__(256) void k_vt(const _Float16* __restrict__ qkv,
                                            _Float16* __restrict__ vt) {
  __shared__ __align__(16) _Float16 T[64][88];  // 176B rows: h8 writes 16B-aligned
  int tid = threadIdx.x;
  int h = blockIdx.x & 15;
  int sb = (blockIdx.x >> 4) << 6;
  const _Float16* src = qkv + 2 * EMB + h * HD;
#pragma unroll
  for (int i = 0; i < 3; ++i) {
    int u = i * 256 + tid;  // 640 h8 units: row=u/10, c8=u%10
    if (u < 640) {
      int row = u / 10, c8 = u % 10;
      *(h8*)&T[row][c8 * 8] = *(const h8*)(src + (size_t)(sb + row) * QKV_LD + c8 * 8);
    }
  }
  __syncthreads();
#pragma unroll
  for (int i = 0; i < 5; ++i) {
    int u = i * 256 + tid;  // 1280 h4 units: d=u>>4, s4=u&15
    int d = u >> 4, s4 = u & 15;
    h4 o;
#pragma unroll
    for (int j = 0; j < 4; ++j) o[j] = T[s4 * 4 + j][d];
    *(h4*)(vt + (size_t)(h * HD + d) * SEQ + sb + s4 * 4) = o;
  }
}

// ---------------- Flash attention: R12 EXACT (best verified, 178 us) ----------------
// KVBLK=128, 8 waves, XCD head map, exp2 softmax, Vt[80][136] direct h8 staging.
__global__ __launch_bounds__(512) void k_attn(const _Float16* __restrict__ qkv,
                                              const _Float16* __restrict__ vt,
                                              _Float16* __restrict__ out) {
  __shared__ _Float16 Kl[128][84];                // 168B rows (verified geometry)
  __shared__ __align__(16) _Float16 Vt[80][136];  // 272B rows: h8 stores 16B-aligned
  int tid = threadIdx.x;
  int lane = tid & 63, wave = tid >> 6;   // wave 0..7
  int l15 = lane & 15, g = lane >> 4;
  int bid = blockIdx.x;
  // XCD-aware bijective remap (512 blocks): xcd = bid&7 gets heads {2*xcd, 2*xcd+1}
  int xcd = bid & 7, rest = bid >> 3;
  int h = (xcd << 1) | (rest & 1);
  int qb = rest >> 1;                     // 0..31

  // Q fragments (B-operand layout): Q[q=l15][d = ks*16 + g*4 + j]
  int qrow = qb * 128 + wave * 16 + l15;
  const _Float16* qp = qkv + (size_t)qrow * QKV_LD + h * HD;
  h4 qf[5];
#pragma unroll
  for (int ks = 0; ks < 5; ks++) qf[ks] = *(const h4*)(qp + ks * 16 + g * 4);

  // K staging: 2560 h4-units (128 rows x 20): u = i*512 + tid, row=u/20, q4=u%20
  const _Float16* gk[5];
  _Float16* lk[5];
#pragma unroll
  for (int i = 0; i < 5; i++) {
    int u = i * 512 + tid;
    gk[i] = qkv + EMB + h * HD + (size_t)(u / 20) * QKV_LD + (u % 20) * 4;
    lk[i] = &Kl[u / 20][(u % 20) * 4];
  }
  // V staging: 1280 h8-units (80 rows x 16 chunks): u = {tid, 512+tid, 1024+(tid&255)}
  int u0 = tid, u1 = 512 + tid, u2 = 1024 + (tid & 255);
  const _Float16* gv0 = vt + (size_t)(h * HD + (u0 >> 4)) * SEQ + (u0 & 15) * 8;
  const _Float16* gv1 = vt + (size_t)(h * HD + (u1 >> 4)) * SEQ + (u1 & 15) * 8;
  const _Float16* gv2 = vt + (size_t)(h * HD + (u2 >> 4)) * SEQ + (u2 & 15) * 8;
  _Float16* lv0 = &Vt[u0 >> 4][(u0 & 15) * 8];
  _Float16* lv1 = &Vt[u1 >> 4][(u1 & 15) * 8];
  _Float16* lv2 = &Vt[u2 >> 4][(u2 & 15) * 8];

  float m = -1e30f, lsum = 0.f;
  f4 O[5];
#pragma unroll
  for (int d = 0; d < 5; d++) O[d] = (f4)0.f;

  for (int t = 0; t < 32; t++) {
    __syncthreads();
    // stage K tile [128][80] (linear, conflict-free 168B rows)
    size_t ka = (size_t)t * (size_t)(128 * QKV_LD);
    int va = t * 128;
    *(h4*)lk[0] = *(const h4*)(gk[0] + ka);
    *(h4*)lk[1] = *(const h4*)(gk[1] + ka);
    *(h4*)lk[2] = *(const h4*)(gk[2] + ka);
    *(h4*)lk[3] = *(const h4*)(gk[3] + ka);
    *(h4*)lk[4] = *(const h4*)(gk[4] + ka);
    // stage V^T tile [80][128] (direct aligned h8 stores)
    *(h8*)lv0 = *(const h8*)(gv0 + va);
    *(h8*)lv1 = *(const h8*)(gv1 + va);
    if (tid < 256) *(h8*)lv2 = *(const h8*)(gv2 + va);
    __syncthreads();

    // QK^T -> S^T tile (128 kv x 16 q), fp32 (verified fragment maps, kvs 0..7)
    f4 st[8];
#pragma unroll
    for (int kvs = 0; kvs < 8; kvs++) st[kvs] = (f4)0.f;
#pragma unroll
    for (int kvs = 0; kvs < 8; kvs++)
#pragma unroll
      for (int ks = 0; ks < 5; ks++) {
        h4 a = *(const h4*)&Kl[kvs * 16 + l15][ks * 16 + g * 4];
        st[kvs] = __builtin_amdgcn_mfma_f32_16x16x16f16(a, qf[ks], st[kvs], 0, 0, 0);
      }

    // online softmax — exp2 domain (log2e folded into Q), full rescale per tile
    float pm = -1e30f;
#pragma unroll
    for (int kvs = 0; kvs < 8; kvs++)
#pragma unroll
      for (int r = 0; r < 4; r++) pm = fmaxf(pm, st[kvs][r]);
    pm = fmaxf(pm, __shfl_xor(pm, 16));
    pm = fmaxf(pm, __shfl_xor(pm, 32));
    float mn = fmaxf(m, pm);
    float fac = __builtin_amdgcn_exp2f(m - mn);
    float rs = 0.f;
    h4 pb[8];
#pragma unroll
    for (int kvs = 0; kvs < 8; kvs++)
#pragma unroll
      for (int r = 0; r < 4; r++) {
        float p = __builtin_amdgcn_exp2f(st[kvs][r] - mn);
        rs += p;
        pb[kvs][r] = (_Float16)p;
      }
    rs += __shfl_xor(rs, 16);
    rs += __shfl_xor(rs, 32);
    lsum = lsum * fac + rs;
    m = mn;
#pragma unroll
    for (int d = 0; d < 5; d++) O[d] *= fac;

    // PV (verified maps): O^T[d][q] += V^T[d][kv] * P^T[kv][q], kvs 0..7
#pragma unroll
    for (int d5 = 0; d5 < 5; d5++)
#pragma unroll
      for (int kvs = 0; kvs < 8; kvs++) {
        h4 a = *(const h4*)&Vt[d5 * 16 + l15][kvs * 16 + g * 4];
        O[d5] = __builtin_amdgcn_mfma_f32_16x16x16f16(a, pb[kvs], O[d5], 0, 0, 0);
      }
  }

  float inv = 1.0f / lsum;
  _Float16* op = out + (size_t)qrow * EMB + h * HD;
#pragma unroll
  for (int d5 = 0; d5 < 5; d5++) {
    h4 o;
#pragma unroll
    for (int r = 0; r < 4; r++) o[r] = (_Float16)(O[d5][r] * inv);
    *(h4*)(op + d5 * 16 + g * 4) = o;
  }
}

extern "C" void kernel_launch(void* const* d_in, const int* in_sizes, int n_in,
                              void* d_out, int out_size, void* d_ws, size_t ws_size,
                              hipStream_t stream) {
  const float* hidden = (const float*)d_in[0];
  const float* cosb   = (const float*)d_in[1];
  const float* sinb   = (const float*)d_in[2];
  const float* Wqkv   = (const float*)d_in[3];
  const float* bqkv   = (const float*)d_in[4];
  const float* Wproj  = (const float*)d_in[5];
  const float* bproj  = (const float*)d_in[6];

  // ws layout — max footprint 55,050,240 B (round-1/7 PROVEN bound):
  //   Ah   @ 0        : 10485760  hidden f16, later attention output
  //   WqT  @ 10485760 :  9830400  dead after QKV GEMM
  //   VT   @ 10485760 : 10485760  written by k_vt AFTER the GEMM (over WqT)
  //   WpT  @ 20316160 :  3276800  written AFTER attention (over VT tail; VT dead)
  //   qkvb @ 23592960 : 31457280
  char* ws = (char*)d_ws;
  _Float16* Ah   = (_Float16*)(ws);
  _Float16* WqT  = (_Float16*)(ws + 10485760);
  _Float16* VT   = (_Float16*)(ws + 10485760);
  _Float16* WpT  = (_Float16*)(ws + 20316160);
  _Float16* qkvb = (_Float16*)(ws + 23592960);

  k_convert<<<SEQ * EMB / 4 / 256, 256, 0, stream>>>(hidden, Ah, SEQ * EMB / 4);
  k_transpose<<<(EMB / 64) * (3 * EMB / 64), 256, 0, stream>>>(Wqkv, WqT, EMB, 3 * EMB);
  k_gemm<false><<<(SEQ / 128) * (3 * EMB / 128), 256, 0, stream>>>(
      Ah, WqT, bqkv, (void*)qkvb, SEQ, 3 * EMB, EMB);
  k_rope<<<(SEQ * NH * 10) / 256, 256, 0, stream>>>(qkvb, cosb, sinb);
  k_vt<<<NH * (SEQ / 64), 256, 0, stream>>>(qkvb, VT);            // VT over dead WqT
  k_attn<<<NH * (SEQ / 128), 512, 0, stream>>>(qkvb, VT, Ah);     // Ah's hidden is dead
  k_transpose<<<(EMB / 64) * (EMB / 64), 256, 0, stream>>>(Wproj, WpT, EMB, EMB);
  k_gemm<true><<<(SEQ / 128) * (EMB / 128), 256, 0, stream>>>(
      Ah, WpT, bproj, d_out, SEQ, EMB, EMB);
}

// Round 16
// 277.251 us; speedup vs baseline: 1.1507x; 1.0239x over previous
//
#include <hip/hip_runtime.h>
#include <hip/hip_bf16.h>
#include <cstdint>
#include <cstddef>

typedef _Float16 h2 __attribute__((ext_vector_type(2)));
typedef _Float16 h4 __attribute__((ext_vector_type(4)));
typedef _Float16 h8 __attribute__((ext_vector_type(8)));
typedef float    f4 __attribute__((ext_vector_type(4)));

#define SEQ 4096
#define EMB 1280
#define NH 16
#define HD 80
#define QKV_LD 3840

// ---------------- transpose + convert: in (R,C) fp32 -> out (C,R) f16 ----------------
__global__ __launch_bounds__(256) void k_transpose(const float* __restrict__ in,
                                                   _Float16* __restrict__ out, int R, int C) {
  __shared__ _Float16 tile[64][68];
  int ct = C >> 6;
  int rB = (blockIdx.x / ct) << 6;
  int cB = (blockIdx.x % ct) << 6;
#pragma unroll 4
  for (int i = 0; i < 16; i++) {
    int idx = i * 256 + threadIdx.x;
    int r = idx >> 6, c = idx & 63;
    tile[r][c] = (_Float16)in[(size_t)(rB + r) * C + cB + c];
  }
  __syncthreads();
#pragma unroll 4
  for (int i = 0; i < 16; i++) {
    int idx = i * 256 + threadIdx.x;
    int c = idx >> 6, r = idx & 63;
    out[(size_t)(cB + c) * R + rB + r] = tile[r][c];
  }
}

// ---------------- GEMM v16: R15-verified BK=64 skeleton; A_F32 folds the fp32->f16
// convert into A-staging (reads 32B fp32/thread, cvt, h8 LDS store). ----------------
template <bool A_F32, bool OUT_F32>
__global__ __launch_bounds__(256) void k_gemm(const void* __restrict__ Aptr,
                                              const _Float16* __restrict__ B,
                                              const float* __restrict__ bias,
                                              void* __restrict__ Cout,
                                              int M, int N, int K) {
  __shared__ _Float16 As[128][72];
  __shared__ _Float16 Bs[128][72];
  int tid = threadIdx.x;
  int lane = tid & 63, wave = tid >> 6;
  int wr = wave >> 1, wc = wave & 1;
  int l15 = lane & 15, g = lane >> 4;
  int nt = N >> 7;
  int mBase = (blockIdx.x / nt) << 7;
  int nBase = (blockIdx.x % nt) << 7;

  f4 acc[4][4];
#pragma unroll
  for (int i = 0; i < 4; i++)
#pragma unroll
    for (int j = 0; j < 4; j++) acc[i][j] = (f4)0.f;

  for (int kt = 0; kt < K; kt += 64) {
    __syncthreads();
#pragma unroll
    for (int i = 0; i < 4; i++) {
      int p = i * 256 + tid;   // 0..1023: r = p>>3, c = p&7
      int r = p >> 3, c = p & 7;
      if (A_F32) {
        const float* Af = (const float*)Aptr;
        f4 v0 = *(const f4*)(Af + (size_t)(mBase + r) * K + kt + c * 8);
        f4 v1 = *(const f4*)(Af + (size_t)(mBase + r) * K + kt + c * 8 + 4);
        h8 o;
        o[0] = (_Float16)v0[0]; o[1] = (_Float16)v0[1];
        o[2] = (_Float16)v0[2]; o[3] = (_Float16)v0[3];
        o[4] = (_Float16)v1[0]; o[5] = (_Float16)v1[1];
        o[6] = (_Float16)v1[2]; o[7] = (_Float16)v1[3];
        *(h8*)&As[r][c * 8] = o;
      } else {
        const _Float16* Ah = (const _Float16*)Aptr;
        *(h8*)&As[r][c * 8] = *(const h8*)(Ah + (size_t)(mBase + r) * K + kt + c * 8);
      }
      *(h8*)&Bs[r][c * 8] = *(const h8*)(B + (size_t)(nBase + r) * K + kt + c * 8);
    }
    __syncthreads();
#pragma unroll
    for (int kk = 0; kk < 2; kk++) {
      h8 af[4], bf[4];
#pragma unroll
      for (int i = 0; i < 4; i++)
        af[i] = *(const h8*)&As[wr * 64 + i * 16 + l15][kk * 32 + g * 8];
#pragma unroll
      for (int j = 0; j < 4; j++)
        bf[j] = *(const h8*)&Bs[wc * 64 + j * 16 + l15][kk * 32 + g * 8];
#pragma unroll
      for (int i = 0; i < 4; i++)
#pragma unroll
        for (int j = 0; j < 4; j++)
          acc[i][j] = __builtin_amdgcn_mfma_f32_16x16x32_f16(bf[j], af[i], acc[i][j], 0, 0, 0);
    }
  }

#pragma unroll
  for (int i = 0; i < 4; i++)
#pragma unroll
    for (int j = 0; j < 4; j++) {
      int row  = mBase + wr * 64 + i * 16 + l15;
      int colb = nBase + wc * 64 + j * 16 + g * 4;
      f4 bv = *(const f4*)(bias + colb);
      f4 v  = acc[i][j] + bv;
      if (OUT_F32) {
        *(f4*)&((float*)Cout)[(size_t)row * N + colb] = v;
      } else {
        h4 o; o[0] = (_Float16)v[0]; o[1] = (_Float16)v[1];
        o[2] = (_Float16)v[2]; o[3] = (_Float16)v[3];
        *(h4*)&((_Float16*)Cout)[(size_t)row * N + colb] = o;
      }
    }
}

// ---------------- RoPE: in-place f16. Q gets 80^-0.5 * log2(e) folded in ----------------
// COUPLED with k_attn's exp2-domain softmax. (Verified R11/R12/R15.)
__global__ __launch_bounds__(256) void k_rope(_Float16* __restrict__ qkv,
                                              const float* __restrict__ cosb,
                                              const float* __restrict__ sinb) {
  int idx = blockIdx.x * 256 + threadIdx.x;  // 4096*16*10
  int s = idx / 160;
  int rem = idx % 160;
  int h = rem / 10;
  int d4 = (rem % 10) * 4;
  const float qscale = 0.16129821086f;  // 80^-0.5 * log2(e)
  f4 c1 = *(const f4*)(cosb + s * 80 + d4);
  f4 s1 = *(const f4*)(sinb + s * 80 + d4);
  f4 c2 = *(const f4*)(cosb + s * 80 + d4 + 40);
  f4 s2 = *(const f4*)(sinb + s * 80 + d4 + 40);
  {
    _Float16* p = qkv + (size_t)s * QKV_LD + h * HD + d4;
    h4 x1 = *(h4*)p, x2 = *(h4*)(p + 40);
    h4 o1, o2;
#pragma unroll
    for (int j = 0; j < 4; j++) {
      float a = (float)x1[j], b = (float)x2[j];
      o1[j] = (_Float16)((a * c1[j] - b * s1[j]) * qscale);
      o2[j] = (_Float16)((b * c2[j] + a * s2[j]) * qscale);
    }
    *(h4*)p = o1; *(h4*)(p + 40) = o2;
  }
  {
    _Float16* p = qkv + (size_t)s * QKV_LD + EMB + h * HD + d4;
    h4 x1 = *(h4*)p, x2 = *(h4*)(p + 40);
    h4 o1, o2;
#pragma unroll
    for (int j = 0; j < 4; j++) {
      float a = (float)x1[j], b = (float)x2[j];
      o1[j] = (_Float16)(a * c1[j] - b * s1[j]);
      o2[j] = (_Float16)(b * c2[j] + a * s2[j]);
    }
    *(h4*)p = o1; *(h4*)(p + 40) = o2;
  }
}

// ---------------- V global transpose: VT[(h*80+d)*SEQ + s] = V[s][h*80+d] ----------------
__global__ __launch_bounds__(256) void k_vt(const _Float16* __restrict__ qkv,
                                            _Float16* __restrict__ vt) {
  __shared__ __align__(16) _Float16 T[64][88];  // 176B rows: h8 writes 16B-aligned
  int tid = threadIdx.x;
  int h = blockIdx.x & 15;
  int sb = (blockIdx.x >> 4) << 6;
  const _Float16* src = qkv + 2 * EMB + h * HD;
#pragma unroll
  for (int i = 0; i < 3; ++i) {
    int u = i * 256 + tid;  // 640 h8 units: row=u/10, c8=u%10
    if (u < 640) {
      int row = u / 10, c8 = u % 10;
      *(h8*)&T[row][c8 * 8] = *(const h8*)(src + (size_t)(sb + row) * QKV_LD + c8 * 8);
    }
  }
  __syncthreads();
#pragma unroll
  for (int i = 0; i < 5; ++i) {
    int u = i * 256 + tid;  // 1280 h4 units: d=u>>4, s4=u&15
    int d = u >> 4, s4 = u & 15;
    h4 o;
#pragma unroll
    for (int j = 0; j < 4; ++j) o[j] = T[s4 * 4 + j][d];
    *(h4*)(vt + (size_t)(h * HD + d) * SEQ + sb + s4 * 4) = o;
  }
}

// ---------------- Flash attention: R12/R15 EXACT structure + defer-max (THR=5) -------
// KVBLK=128, 8 waves, XCD head map, exp2 softmax, Vt[80][136] direct h8 staging.
__global__ __launch_bounds__(512) void k_attn(const _Float16* __restrict__ qkv,
                                              const _Float16* __restrict__ vt,
                                              _Float16* __restrict__ out) {
  __shared__ _Float16 Kl[128][84];                // 168B rows (verified geometry)
  __shared__ __align__(16) _Float16 Vt[80][136];  // 272B rows: h8 stores 16B-aligned
  int tid = threadIdx.x;
  int lane = tid & 63, wave = tid >> 6;   // wave 0..7
  int l15 = lane & 15, g = lane >> 4;
  int bid = blockIdx.x;
  // XCD-aware bijective remap (512 blocks): xcd = bid&7 gets heads {2*xcd, 2*xcd+1}
  int xcd = bid & 7, rest = bid >> 3;
  int h = (xcd << 1) | (rest & 1);
  int qb = rest >> 1;                     // 0..31

  // Q fragments (B-operand layout): Q[q=l15][d = ks*16 + g*4 + j]
  int qrow = qb * 128 + wave * 16 + l15;
  const _Float16* qp = qkv + (size_t)qrow * QKV_LD + h * HD;
  h4 qf[5];
#pragma unroll
  for (int ks = 0; ks < 5; ks++) qf[ks] = *(const h4*)(qp + ks * 16 + g * 4);

  // K staging: 2560 h4-units (128 rows x 20): u = i*512 + tid, row=u/20, q4=u%20
  const _Float16* gk[5];
  _Float16* lk[5];
#pragma unroll
  for (int i = 0; i < 5; i++) {
    int u = i * 512 + tid;
    gk[i] = qkv + EMB + h * HD + (size_t)(u / 20) * QKV_LD + (u % 20) * 4;
    lk[i] = &Kl[u / 20][(u % 20) * 4];
  }
  // V staging: 1280 h8-units (80 rows x 16 chunks): u = {tid, 512+tid, 1024+(tid&255)}
  int u0 = tid, u1 = 512 + tid, u2 = 1024 + (tid & 255);
  const _Float16* gv0 = vt + (size_t)(h * HD + (u0 >> 4)) * SEQ + (u0 & 15) * 8;
  const _Float16* gv1 = vt + (size_t)(h * HD + (u1 >> 4)) * SEQ + (u1 & 15) * 8;
  const _Float16* gv2 = vt + (size_t)(h * HD + (u2 >> 4)) * SEQ + (u2 & 15) * 8;
  _Float16* lv0 = &Vt[u0 >> 4][(u0 & 15) * 8];
  _Float16* lv1 = &Vt[u1 >> 4][(u1 & 15) * 8];
  _Float16* lv2 = &Vt[u2 >> 4][(u2 & 15) * 8];

  float m = -1e30f, lsum = 0.f;
  f4 O[5];
#pragma unroll
  for (int d = 0; d < 5; d++) O[d] = (f4)0.f;

  for (int t = 0; t < 32; t++) {
    __syncthreads();
    // stage K tile [128][80] (linear, conflict-free 168B rows)
    size_t ka = (size_t)t * (size_t)(128 * QKV_LD);
    int va = t * 128;
    *(h4*)lk[0] = *(const h4*)(gk[0] + ka);
    *(h4*)lk[1] = *(const h4*)(gk[1] + ka);
    *(h4*)lk[2] = *(const h4*)(gk[2] + ka);
    *(h4*)lk[3] = *(const h4*)(gk[3] + ka);
    *(h4*)lk[4] = *(const h4*)(gk[4] + ka);
    // stage V^T tile [80][128] (direct aligned h8 stores)
    *(h8*)lv0 = *(const h8*)(gv0 + va);
    *(h8*)lv1 = *(const h8*)(gv1 + va);
    if (tid < 256) *(h8*)lv2 = *(const h8*)(gv2 + va);
    __syncthreads();

    // QK^T -> S^T tile (128 kv x 16 q), fp32 (verified fragment maps, kvs 0..7)
    f4 st[8];
#pragma unroll
    for (int kvs = 0; kvs < 8; kvs++) st[kvs] = (f4)0.f;
#pragma unroll
    for (int kvs = 0; kvs < 8; kvs++)
#pragma unroll
      for (int ks = 0; ks < 5; ks++) {
        h4 a = *(const h4*)&Kl[kvs * 16 + l15][ks * 16 + g * 4];
        st[kvs] = __builtin_amdgcn_mfma_f32_16x16x16f16(a, qf[ks], st[kvs], 0, 0, 0);
      }

    // online softmax — exp2 domain, DEFER-MAX (THR=5): skip the O/lsum rescale
    // unless some row's tile-max exceeds the running max by >5 (P bounded 2^5).
    float pm = -1e30f;
#pragma unroll
    for (int kvs = 0; kvs < 8; kvs++)
#pragma unroll
      for (int r = 0; r < 4; r++) pm = fmaxf(pm, st[kvs][r]);
    pm = fmaxf(pm, __shfl_xor(pm, 16));
    pm = fmaxf(pm, __shfl_xor(pm, 32));
    if (__any(pm > m + 5.f)) {
      float mn = fmaxf(m, pm);
      float fac = __builtin_amdgcn_exp2f(m - mn);
      lsum *= fac;
#pragma unroll
      for (int d = 0; d < 5; d++) O[d] *= fac;
      m = mn;
    }
    float rs = 0.f;
    h4 pb[8];
#pragma unroll
    for (int kvs = 0; kvs < 8; kvs++)
#pragma unroll
      for (int r = 0; r < 4; r++) {
        float p = __builtin_amdgcn_exp2f(st[kvs][r] - m);
        rs += p;
        pb[kvs][r] = (_Float16)p;
      }
    rs += __shfl_xor(rs, 16);
    rs += __shfl_xor(rs, 32);
    lsum += rs;

    // PV (verified maps): O^T[d][q] += V^T[d][kv] * P^T[kv][q], kvs 0..7
#pragma unroll
    for (int d5 = 0; d5 < 5; d5++)
#pragma unroll
      for (int kvs = 0; kvs < 8; kvs++) {
        h4 a = *(const h4*)&Vt[d5 * 16 + l15][kvs * 16 + g * 4];
        O[d5] = __builtin_amdgcn_mfma_f32_16x16x16f16(a, pb[kvs], O[d5], 0, 0, 0);
      }
  }

  float inv = 1.0f / lsum;
  _Float16* op = out + (size_t)qrow * EMB + h * HD;
#pragma unroll
  for (int d5 = 0; d5 < 5; d5++) {
    h4 o;
#pragma unroll
    for (int r = 0; r < 4; r++) o[r] = (_Float16)(O[d5][r] * inv);
    *(h4*)(op + d5 * 16 + g * 4) = o;
  }
}

extern "C" void kernel_launch(void* const* d_in, const int* in_sizes, int n_in,
                              void* d_out, int out_size, void* d_ws, size_t ws_size,
                              hipStream_t stream) {
  const float* hidden = (const float*)d_in[0];
  const float* cosb   = (const float*)d_in[1];
  const float* sinb   = (const float*)d_in[2];
  const float* Wqkv   = (const float*)d_in[3];
  const float* bqkv   = (const float*)d_in[4];
  const float* Wproj  = (const float*)d_in[5];
  const float* bproj  = (const float*)d_in[6];

  // ws layout — max footprint 55,050,240 B (PROVEN bound):
  //   Ah   @ 0        : 10485760  attention output f16 (no longer pre-filled)
  //   WqT  @ 10485760 :  9830400  dead after QKV GEMM
  //   VT   @ 10485760 : 10485760  written by k_vt AFTER the GEMM (over WqT)
  //   WpT  @ 20316160 :  3276800  written AFTER attention (over VT tail; VT dead)
  //   qkvb @ 23592960 : 31457280
  char* ws = (char*)d_ws;
  _Float16* Ah   = (_Float16*)(ws);
  _Float16* WqT  = (_Float16*)(ws + 10485760);
  _Float16* VT   = (_Float16*)(ws + 10485760);
  _Float16* WpT  = (_Float16*)(ws + 20316160);
  _Float16* qkvb = (_Float16*)(ws + 23592960);

  k_transpose<<<(EMB / 64) * (3 * EMB / 64), 256, 0, stream>>>(Wqkv, WqT, EMB, 3 * EMB);
  k_gemm<true, false><<<(SEQ / 128) * (3 * EMB / 128), 256, 0, stream>>>(
      (const void*)hidden, WqT, bqkv, (void*)qkvb, SEQ, 3 * EMB, EMB);
  k_rope<<<(SEQ * NH * 10) / 256, 256, 0, stream>>>(qkvb, cosb, sinb);
  k_vt<<<NH * (SEQ / 64), 256, 0, stream>>>(qkvb, VT);            // VT over dead WqT
  k_attn<<<NH * (SEQ / 128), 512, 0, stream>>>(qkvb, VT, Ah);
  k_transpose<<<(EMB / 64) * (EMB / 64), 256, 0, stream>>>(Wproj, WpT, EMB, EMB);
  k_gemm<false, true><<<(SEQ / 128) * (EMB / 128), 256, 0, stream>>>(
      (const void*)Ah, WpT, bproj, d_out, SEQ, EMB, EMB);
}

// Round 17
// 265.119 us; speedup vs baseline: 1.2034x; 1.0458x over previous
//
#include <hip/hip_runtime.h>
#include <hip/hip_bf16.h>
#include <cstdint>
#include <cstddef>

typedef _Float16 h2 __attribute__((ext_vector_type(2)));
typedef _Float16 h4 __attribute__((ext_vector_type(4)));
typedef _Float16 h8 __attribute__((ext_vector_type(8)));
typedef float    f4 __attribute__((ext_vector_type(4)));

#define SEQ 4096
#define EMB 1280
#define NH 16
#define HD 80
#define QK_LD 2560   // Q+K only buffer stride (V is diverted to VT at GEMM epilogue)

// ---------------- transpose + convert: in (R,C) fp32 -> out (C,R) f16 ----------------
__global__ __launch_bounds__(256) void k_transpose(const float* __restrict__ in,
                                                   _Float16* __restrict__ out, int R, int C) {
  __shared__ _Float16 tile[64][68];
  int ct = C >> 6;
  int rB = (blockIdx.x / ct) << 6;
  int cB = (blockIdx.x % ct) << 6;
#pragma unroll 4
  for (int i = 0; i < 16; i++) {
    int idx = i * 256 + threadIdx.x;
    int r = idx >> 6, c = idx & 63;
    tile[r][c] = (_Float16)in[(size_t)(rB + r) * C + cB + c];
  }
  __syncthreads();
#pragma unroll 4
  for (int i = 0; i < 16; i++) {
    int idx = i * 256 + threadIdx.x;
    int c = idx >> 6, r = idx & 63;
    out[(size_t)(cB + c) * R + rB + r] = tile[r][c];
  }
}

// ---------------- GEMM v17: R15/R16-verified BK=64 skeleton.
// A_F32: fold fp32->f16 convert into A staging (verified R16).
// V_SPLIT: blocks with nBase>=2560 write C transposed (f16) into vt instead of C
//          (fuses the old k_vt); Q/K blocks write to C with stride ldc.
template <bool A_F32, bool OUT_F32, bool V_SPLIT>
__global__ __launch_bounds__(256) void k_gemm(const void* __restrict__ Aptr,
                                              const _Float16* __restrict__ B,
                                              const float* __restrict__ bias,
                                              void* __restrict__ Cout,
                                              _Float16* __restrict__ vt,
                                              int M, int N, int K, int ldc) {
  __shared__ _Float16 As[128][72];
  __shared__ _Float16 Bs[128][72];
  int tid = threadIdx.x;
  int lane = tid & 63, wave = tid >> 6;
  int wr = wave >> 1, wc = wave & 1;
  int l15 = lane & 15, g = lane >> 4;
  int nt = N >> 7;
  int mBase = (blockIdx.x / nt) << 7;
  int nBase = (blockIdx.x % nt) << 7;

  f4 acc[4][4];
#pragma unroll
  for (int i = 0; i < 4; i++)
#pragma unroll
    for (int j = 0; j < 4; j++) acc[i][j] = (f4)0.f;

  for (int kt = 0; kt < K; kt += 64) {
    __syncthreads();
#pragma unroll
    for (int i = 0; i < 4; i++) {
      int p = i * 256 + tid;   // 0..1023: r = p>>3, c = p&7
      int r = p >> 3, c = p & 7;
      if (A_F32) {
        const float* Af = (const float*)Aptr;
        f4 v0 = *(const f4*)(Af + (size_t)(mBase + r) * K + kt + c * 8);
        f4 v1 = *(const f4*)(Af + (size_t)(mBase + r) * K + kt + c * 8 + 4);
        h8 o;
        o[0] = (_Float16)v0[0]; o[1] = (_Float16)v0[1];
        o[2] = (_Float16)v0[2]; o[3] = (_Float16)v0[3];
        o[4] = (_Float16)v1[0]; o[5] = (_Float16)v1[1];
        o[6] = (_Float16)v1[2]; o[7] = (_Float16)v1[3];
        *(h8*)&As[r][c * 8] = o;
      } else {
        const _Float16* Ah = (const _Float16*)Aptr;
        *(h8*)&As[r][c * 8] = *(const h8*)(Ah + (size_t)(mBase + r) * K + kt + c * 8);
      }
      *(h8*)&Bs[r][c * 8] = *(const h8*)(B + (size_t)(nBase + r) * K + kt + c * 8);
    }
    __syncthreads();
#pragma unroll
    for (int kk = 0; kk < 2; kk++) {
      h8 af[4], bf[4];
#pragma unroll
      for (int i = 0; i < 4; i++)
        af[i] = *(const h8*)&As[wr * 64 + i * 16 + l15][kk * 32 + g * 8];
#pragma unroll
      for (int j = 0; j < 4; j++)
        bf[j] = *(const h8*)&Bs[wc * 64 + j * 16 + l15][kk * 32 + g * 8];
#pragma unroll
      for (int i = 0; i < 4; i++)
#pragma unroll
        for (int j = 0; j < 4; j++)
          acc[i][j] = __builtin_amdgcn_mfma_f32_16x16x32_f16(bf[j], af[i], acc[i][j], 0, 0, 0);
    }
  }

  bool vblk = V_SPLIT && (nBase >= 2560);
#pragma unroll
  for (int i = 0; i < 4; i++)
#pragma unroll
    for (int j = 0; j < 4; j++) {
      int row  = mBase + wr * 64 + i * 16 + l15;
      int colb = nBase + wc * 64 + j * 16 + g * 4;
      f4 bv = *(const f4*)(bias + colb);
      f4 v  = acc[i][j] + bv;
      if (vblk) {
        // transposed f16 store into VT[(col-2560)*SEQ + row]; lanes vary row ->
        // 16x2B contiguous runs, HW-coalesced.
#pragma unroll
        for (int r = 0; r < 4; r++)
          vt[(size_t)(colb - 2560 + r) * SEQ + row] = (_Float16)v[r];
      } else if (OUT_F32) {
        *(f4*)&((float*)Cout)[(size_t)row * ldc + colb] = v;
      } else {
        h4 o; o[0] = (_Float16)v[0]; o[1] = (_Float16)v[1];
        o[2] = (_Float16)v[2]; o[3] = (_Float16)v[3];
        *(h4*)&((_Float16*)Cout)[(size_t)row * ldc + colb] = o;
      }
    }
}

// ---------------- RoPE: in-place f16 on qkQK (stride 2560). Q gets 80^-0.5*log2e ------
__global__ __launch_bounds__(256) void k_rope(_Float16* __restrict__ qk,
                                              const float* __restrict__ cosb,
                                              const float* __restrict__ sinb) {
  int idx = blockIdx.x * 256 + threadIdx.x;  // 4096*16*10
  int s = idx / 160;
  int rem = idx % 160;
  int h = rem / 10;
  int d4 = (rem % 10) * 4;
  const float qscale = 0.16129821086f;  // 80^-0.5 * log2(e)
  f4 c1 = *(const f4*)(cosb + s * 80 + d4);
  f4 s1 = *(const f4*)(sinb + s * 80 + d4);
  f4 c2 = *(const f4*)(cosb + s * 80 + d4 + 40);
  f4 s2 = *(const f4*)(sinb + s * 80 + d4 + 40);
  {
    _Float16* p = qk + (size_t)s * QK_LD + h * HD + d4;
    h4 x1 = *(h4*)p, x2 = *(h4*)(p + 40);
    h4 o1, o2;
#pragma unroll
    for (int j = 0; j < 4; j++) {
      float a = (float)x1[j], b = (float)x2[j];
      o1[j] = (_Float16)((a * c1[j] - b * s1[j]) * qscale);
      o2[j] = (_Float16)((b * c2[j] + a * s2[j]) * qscale);
    }
    *(h4*)p = o1; *(h4*)(p + 40) = o2;
  }
  {
    _Float16* p = qk + (size_t)s * QK_LD + EMB + h * HD + d4;
    h4 x1 = *(h4*)p, x2 = *(h4*)(p + 40);
    h4 o1, o2;
#pragma unroll
    for (int j = 0; j < 4; j++) {
      float a = (float)x1[j], b = (float)x2[j];
      o1[j] = (_Float16)(a * c1[j] - b * s1[j]);
      o2[j] = (_Float16)(b * c2[j] + a * s2[j]);
    }
    *(h4*)p = o1; *(h4*)(p + 40) = o2;
  }
}

// ---------------- Flash attention: R12/R15/R16 EXACT structure; qk stride 2560;
// defer-max (THR=5, verified R16) + deferred lsum reduce (epilogue, fac row-uniform).
__global__ __launch_bounds__(512) void k_attn(const _Float16* __restrict__ qk,
                                              const _Float16* __restrict__ vt,
                                              _Float16* __restrict__ out) {
  __shared__ _Float16 Kl[128][84];                // 168B rows (verified geometry)
  __shared__ __align__(16) _Float16 Vt[80][136];  // 272B rows: h8 stores 16B-aligned
  int tid = threadIdx.x;
  int lane = tid & 63, wave = tid >> 6;   // wave 0..7
  int l15 = lane & 15, g = lane >> 4;
  int bid = blockIdx.x;
  // XCD-aware bijective remap (512 blocks): xcd = bid&7 gets heads {2*xcd, 2*xcd+1}
  int xcd = bid & 7, rest = bid >> 3;
  int h = (xcd << 1) | (rest & 1);
  int qb = rest >> 1;                     // 0..31

  // Q fragments (B-operand layout): Q[q=l15][d = ks*16 + g*4 + j]
  int qrow = qb * 128 + wave * 16 + l15;
  const _Float16* qp = qk + (size_t)qrow * QK_LD + h * HD;
  h4 qf[5];
#pragma unroll
  for (int ks = 0; ks < 5; ks++) qf[ks] = *(const h4*)(qp + ks * 16 + g * 4);

  // K staging: 2560 h4-units (128 rows x 20): u = i*512 + tid, row=u/20, q4=u%20
  const _Float16* gk[5];
  _Float16* lk[5];
#pragma unroll
  for (int i = 0; i < 5; i++) {
    int u = i * 512 + tid;
    gk[i] = qk + EMB + h * HD + (size_t)(u / 20) * QK_LD + (u % 20) * 4;
    lk[i] = &Kl[u / 20][(u % 20) * 4];
  }
  // V staging: 1280 h8-units (80 rows x 16 chunks): u = {tid, 512+tid, 1024+(tid&255)}
  int u0 = tid, u1 = 512 + tid, u2 = 1024 + (tid & 255);
  const _Float16* gv0 = vt + (size_t)(h * HD + (u0 >> 4)) * SEQ + (u0 & 15) * 8;
  const _Float16* gv1 = vt + (size_t)(h * HD + (u1 >> 4)) * SEQ + (u1 & 15) * 8;
  const _Float16* gv2 = vt + (size_t)(h * HD + (u2 >> 4)) * SEQ + (u2 & 15) * 8;
  _Float16* lv0 = &Vt[u0 >> 4][(u0 & 15) * 8];
  _Float16* lv1 = &Vt[u1 >> 4][(u1 & 15) * 8];
  _Float16* lv2 = &Vt[u2 >> 4][(u2 & 15) * 8];

  float m = -1e30f, lsum = 0.f;   // lsum: PER-LANE partial, reduced in epilogue
  f4 O[5];
#pragma unroll
  for (int d = 0; d < 5; d++) O[d] = (f4)0.f;

  for (int t = 0; t < 32; t++) {
    __syncthreads();
    // stage K tile [128][80] (linear, conflict-free 168B rows); global stride QK_LD
    size_t ka = (size_t)t * (size_t)(128 * QK_LD);
    int va = t * 128;
    *(h4*)lk[0] = *(const h4*)(gk[0] + ka);
    *(h4*)lk[1] = *(const h4*)(gk[1] + ka);
    *(h4*)lk[2] = *(const h4*)(gk[2] + ka);
    *(h4*)lk[3] = *(const h4*)(gk[3] + ka);
    *(h4*)lk[4] = *(const h4*)(gk[4] + ka);
    // stage V^T tile [80][128] (direct aligned h8 stores)
    *(h8*)lv0 = *(const h8*)(gv0 + va);
    *(h8*)lv1 = *(const h8*)(gv1 + va);
    if (tid < 256) *(h8*)lv2 = *(const h8*)(gv2 + va);
    __syncthreads();

    // QK^T -> S^T tile (128 kv x 16 q), fp32 (verified fragment maps, kvs 0..7)
    f4 st[8];
#pragma unroll
    for (int kvs = 0; kvs < 8; kvs++) st[kvs] = (f4)0.f;
#pragma unroll
    for (int kvs = 0; kvs < 8; kvs++)
#pragma unroll
      for (int ks = 0; ks < 5; ks++) {
        h4 a = *(const h4*)&Kl[kvs * 16 + l15][ks * 16 + g * 4];
        st[kvs] = __builtin_amdgcn_mfma_f32_16x16x16f16(a, qf[ks], st[kvs], 0, 0, 0);
      }

    // online softmax — exp2 domain, defer-max (THR=5), per-lane lsum
    float pm = -1e30f;
#pragma unroll
    for (int kvs = 0; kvs < 8; kvs++)
#pragma unroll
      for (int r = 0; r < 4; r++) pm = fmaxf(pm, st[kvs][r]);
    pm = fmaxf(pm, __shfl_xor(pm, 16));
    pm = fmaxf(pm, __shfl_xor(pm, 32));
    if (__any(pm > m + 5.f)) {
      float mn = fmaxf(m, pm);
      float fac = __builtin_amdgcn_exp2f(m - mn);
      lsum *= fac;
#pragma unroll
      for (int d = 0; d < 5; d++) O[d] *= fac;
      m = mn;
    }
    float rs = 0.f;
    h4 pb[8];
#pragma unroll
    for (int kvs = 0; kvs < 8; kvs++)
#pragma unroll
      for (int r = 0; r < 4; r++) {
        float p = __builtin_amdgcn_exp2f(st[kvs][r] - m);
        rs += p;
        pb[kvs][r] = (_Float16)p;
      }
    lsum += rs;   // per-lane partial; fac applied above is row-uniform -> sound

    // PV (verified maps): O^T[d][q] += V^T[d][kv] * P^T[kv][q], kvs 0..7
#pragma unroll
    for (int d5 = 0; d5 < 5; d5++)
#pragma unroll
      for (int kvs = 0; kvs < 8; kvs++) {
        h4 a = *(const h4*)&Vt[d5 * 16 + l15][kvs * 16 + g * 4];
        O[d5] = __builtin_amdgcn_mfma_f32_16x16x16f16(a, pb[kvs], O[d5], 0, 0, 0);
      }
  }

  // epilogue: deferred cross-lane lsum reduce
  lsum += __shfl_xor(lsum, 16);
  lsum += __shfl_xor(lsum, 32);
  float inv = 1.0f / lsum;
  _Float16* op = out + (size_t)qrow * EMB + h * HD;
#pragma unroll
  for (int d5 = 0; d5 < 5; d5++) {
    h4 o;
#pragma unroll
    for (int r = 0; r < 4; r++) o[r] = (_Float16)(O[d5][r] * inv);
    *(h4*)(op + d5 * 16 + g * 4) = o;
  }
}

extern "C" void kernel_launch(void* const* d_in, const int* in_sizes, int n_in,
                              void* d_out, int out_size, void* d_ws, size_t ws_size,
                              hipStream_t stream) {
  const float* hidden = (const float*)d_in[0];
  const float* cosb   = (const float*)d_in[1];
  const float* sinb   = (const float*)d_in[2];
  const float* Wqkv   = (const float*)d_in[3];
  const float* bqkv   = (const float*)d_in[4];
  const float* Wproj  = (const float*)d_in[5];
  const float* bproj  = (const float*)d_in[6];

  // ws layout — max footprint 51,773,440 B (< proven 55,050,240 bound):
  //   Ah   @ 0        : 10485760  attention output f16
  //   WqT  @ 10485760 :  9830400  read during QKV GEMM; dead after
  //   WpT  @ 10485760 :  3276800  written AFTER attention (over dead WqT)
  //   qkQK @ 20316160 : 20971520  Q+K (stride 2560), written by QKV GEMM
  //   VT   @ 41287680 : 10485760  V^T, written by QKV GEMM epilogue (fused k_vt)
  char* ws = (char*)d_ws;
  _Float16* Ah   = (_Float16*)(ws);
  _Float16* WqT  = (_Float16*)(ws + 10485760);
  _Float16* WpT  = (_Float16*)(ws + 10485760);
  _Float16* qkQK = (_Float16*)(ws + 20316160);
  _Float16* VT   = (_Float16*)(ws + 41287680);

  k_transpose<<<(EMB / 64) * (3 * EMB / 64), 256, 0, stream>>>(Wqkv, WqT, EMB, 3 * EMB);
  k_gemm<true, false, true><<<(SEQ / 128) * (3 * EMB / 128), 256, 0, stream>>>(
      (const void*)hidden, WqT, bqkv, (void*)qkQK, VT, SEQ, 3 * EMB, EMB, QK_LD);
  k_rope<<<(SEQ * NH * 10) / 256, 256, 0, stream>>>(qkQK, cosb, sinb);
  k_attn<<<NH * (SEQ / 128), 512, 0, stream>>>(qkQK, VT, Ah);
  k_transpose<<<(EMB / 64) * (EMB / 64), 256, 0, stream>>>(Wproj, WpT, EMB, EMB);
  k_gemm<false, true, false><<<(SEQ / 128) * (EMB / 128), 256, 0, stream>>>(
      (const void*)Ah, WpT, bproj, d_out, (_Float16*)nullptr, SEQ, EMB, EMB, EMB);
}